// Round 4
// baseline (95.480 us; speedup 1.0000x reference)
//
#include <hip/hip_runtime.h>
#include <cstddef>

// YOLOv3 loss, MI355X. b=32, scales 13/26/52, 3 anchors, 80 classes, 50 boxes.
// Input order (setup_inputs dict order, interleaved per scale):
//   d_in[4k+0]=output_k (b,255,S,S)  d_in[4k+1]=loc_k (b,3,4,S,S)
//   d_in[4k+2]=cls_k (b,3,80,S,S)    d_in[4k+3]=boxes_k (b,50,4)
// ws: 4 doubles {LL, LC, LK, NPOS}
//
// R3: channel-split blocks. Each block = 256 cells (64 lanes x float4);
// wave w reduces class channels [20w,20w+20) -> partials in LDS; tail phase
// (1 cell/thread) sums partials + conf/IoU/loc. Grid 1536 blocks (75% occ cap)
// WITH float4 ILP (R1 had float4 but 384 blocks; R2 had 1344 blocks but scalar).

constexpr int NC = 80;
constexpr int NA = 3;
constexpr int NM = 50;
constexpr int NB = 32;

__device__ constexpr float ANCW[3][3] = {{116.f,156.f,373.f},{30.f,62.f,59.f},{10.f,16.f,33.f}};
__device__ constexpr float ANCH[3][3] = {{ 90.f,198.f,326.f},{61.f,45.f,119.f},{13.f,30.f,23.f}};

__device__ __forceinline__ float frcp_(float x) { return __builtin_amdgcn_rcpf(x); }
__device__ __forceinline__ float sigmoidf_(float x) { return frcp_(1.0f + __expf(-x)); }

template <int VW>
__device__ __forceinline__ void loadv(const float* __restrict__ p, float (&d)[VW]) {
    if constexpr (VW == 4) {
        const float4 v = *reinterpret_cast<const float4*>(p);
        d[0] = v.x; d[1] = v.y; d[2] = v.z; d[3] = v.w;
    } else {
        d[0] = p[0];
    }
}

__global__ void init_acc_kernel(double* acc) {
    if (threadIdx.x < 4) acc[threadIdx.x] = 0.0;
}

__global__ void finalize_kernel(const double* __restrict__ acc, float* __restrict__ out) {
    out[0] = (float)(5.0 * (acc[0] + acc[1] + acc[2]) / (double)NB / acc[3]);
}

// smem layout (floats): part[4][4][256] = 4096 | sbx[200] | sba[50] | red[16]
constexpr int SMEM_FLOATS = 4096 + 200 + 50 + 16;

template <int SC, int S, int VW, bool COUNT_POS>
__device__ __forceinline__ void process_scale(
    const float* __restrict__ outp, const float* __restrict__ locp,
    const float* __restrict__ clsp, const float* __restrict__ boxp,
    double* __restrict__ acc, float* smem, int rel)
{
    constexpr int SS = S * S;
    constexpr int CELLS = NA * SS;
    constexpr int CPB = 64 * VW;                        // cells per block
    constexpr int BPB = (CELLS + CPB - 1) / CPB;        // blocks per image

    float* part = smem;                                 // [w][q][cell] -> w*1024+q*256+cell
    float* sbx  = smem + 4096;
    float* sba  = sbx + NM * 4;
    float* red  = sba + NM;                             // [4][4]

    const int b   = rel / BPB;
    const int chk = rel % BPB;
    const int tid = threadIdx.x;
    const int w   = tid >> 6;
    const int l   = tid & 63;

    if (tid < NM * 4) sbx[tid] = boxp[(size_t)b * NM * 4 + tid];
    __syncthreads();
    if (tid < NM)
        sba[tid] = (sbx[tid*4+2] - sbx[tid*4+0]) * (sbx[tid*4+3] - sbx[tid*4+1]);

    // ---- class phase: wave w handles channels [20w, 20w+20) for CPB cells ----
    const int cell0 = chk * CPB + l * VW;               // VW cells per lane, same a-panel (SS%VW==0)
    float Z[VW] = {}, A2[VW] = {}, A1[VW] = {}, A0[VW] = {};
    if (cell0 < CELLS) {
        const int a   = cell0 / SS;
        const int rem = cell0 - a * SS;
        const float* opc = outp + (((size_t)b * NA + a) * (5 + NC) + 5 + w * 20) * SS + rem;
        const float* cpc = clsp + (((size_t)b * NA + a) * NC + w * 20) * SS + rem;
        #pragma unroll 5
        for (int cc = 0; cc < 20; ++cc) {
            float L[VW], T[VW];
            loadv<VW>(opc + (size_t)cc * SS, L);
            loadv<VW>(cpc + (size_t)cc * SS, T);
            #pragma unroll
            for (int i = 0; i < VW; ++i) {
                const float e  = __expf(L[i]);
                const float wf = (T[i] > 0.f) ? 1.f : 0.f;
                const float we = wf * e;
                const float wt = wf * T[i];
                Z[i]  += e;
                A2[i]  = fmaf(we, e, A2[i]);
                A1[i]  = fmaf(we, T[i], A1[i]);
                A0[i]  = fmaf(wt, T[i], A0[i]);
            }
        }
    }
    // write partials to LDS (contiguous across lanes -> conflict-free)
    if constexpr (VW == 4) {
        #pragma unroll
        for (int q = 0; q < 4; ++q) {
            const float qa[4][4] = {};
            float4 v;
            v.x = (q==0?Z[0]:q==1?A2[0]:q==2?A1[0]:A0[0]);
            v.y = (q==0?Z[1]:q==1?A2[1]:q==2?A1[1]:A0[1]);
            v.z = (q==0?Z[2]:q==1?A2[2]:q==2?A1[2]:A0[2]);
            v.w = (q==0?Z[3]:q==1?A2[3]:q==2?A1[3]:A0[3]);
            (void)qa;
            *reinterpret_cast<float4*>(&part[w*1024 + q*256 + l*4]) = v;
        }
    } else {
        part[w*1024 + 0*256 + l] = Z[0];
        part[w*1024 + 1*256 + l] = A2[0];
        part[w*1024 + 2*256 + l] = A1[0];
        part[w*1024 + 3*256 + l] = A0[0];
    }
    __syncthreads();

    // ---- tail phase: one cell per thread (VW=1: only wave 0 active) ----
    float ll = 0.f, lc = 0.f, lk = 0.f, np = 0.f;
    const int ct   = (VW == 4) ? tid : l;
    const bool act = (VW == 4) ? true : (w == 0);
    const int cell = chk * CPB + ct;
    if (act && cell < CELLS) {
        const float Zs  = part[0*1024+0*256+ct] + part[1*1024+0*256+ct] + part[2*1024+0*256+ct] + part[3*1024+0*256+ct];
        const float A2s = part[0*1024+1*256+ct] + part[1*1024+1*256+ct] + part[2*1024+1*256+ct] + part[3*1024+1*256+ct];
        const float A1s = part[0*1024+2*256+ct] + part[1*1024+2*256+ct] + part[2*1024+2*256+ct] + part[3*1024+2*256+ct];
        const float A0s = part[0*1024+3*256+ct] + part[1*1024+3*256+ct] + part[2*1024+3*256+ct] + part[3*1024+3*256+ct];

        const int a   = cell / SS;
        const int rem = cell - a * SS;
        const float* op = outp + ((size_t)b * NA + a) * (5 + NC) * SS + rem;
        const float* lp = locp + ((size_t)b * NA + a) * 4 * SS + rem;

        const float tx = op[0 * SS];
        const float ty = op[1 * SS];
        const float tw = op[2 * SS];
        const float th = op[3 * SS];
        const float tc = op[4 * SS];
        const float l0 = lp[0 * SS], l1 = lp[1 * SS], l2 = lp[2 * SS], l3 = lp[3 * SS];

        const bool pos = A0s > 0.f;
        if (pos) {
            const float d0 = tx-l0, d1 = ty-l1, d2 = tw-l2, d3 = th-l3;
            ll = d0*d0 + d1*d1 + d2*d2 + d3*d3;
            if (COUNT_POS) np = 1.f;
        }

        const float aw = ANCW[SC][a] * ((float)S / 416.f);
        const float ah = ANCH[SC][a] * ((float)S / 416.f);
        const int y = rem / S;
        const int x = rem - y * S;
        const float sx = sigmoidf_(tx) + (float)x;
        const float sy = sigmoidf_(ty) + (float)y;
        const float bw = __expf(tw) * aw;
        const float bh = __expf(th) * ah;
        const float x1 = sx - bw * 0.5f, y1 = sy - bh * 0.5f;
        const float x2 = sx + bw * 0.5f, y2 = sy + bh * 0.5f;
        const float area = (x2 - x1) * (y2 - y1);

        float bn = 0.f, bd = 1.f;                       // best IoU as fraction
        #pragma unroll 10
        for (int j = 0; j < NM; ++j) {
            const float bx1 = sbx[j*4+0], by1 = sbx[j*4+1];
            const float bx2 = sbx[j*4+2], by2 = sbx[j*4+3];
            const float iw = fmaxf(fminf(x2, bx2) - fmaxf(x1, bx1), 0.f);
            const float ih = fmaxf(fminf(y2, by2) - fmaxf(y1, by1), 0.f);
            const float inter = iw * ih;
            const float uni   = area + sba[j] - inter;
            const bool upd = inter * bd > bn * uni;
            bn = upd ? inter : bn;
            bd = upd ? uni   : bd;
        }

        const float best  = bn / bd;                    // exact div, tail-only
        const float cpred = sigmoidf_(tc);
        const float m2    = pos ? 1.f : 0.01f;
        const float d     = cpred - best;
        lc = m2 * d * d;

        const float invZ = 1.f / Zs;
        lk = fmaf(A2s * invZ, invZ, fmaf(-2.f * A1s, invZ, A0s));
    }

    // ---- block reduction ----
    for (int off = 32; off > 0; off >>= 1) {
        ll += __shfl_down(ll, off);
        lc += __shfl_down(lc, off);
        lk += __shfl_down(lk, off);
        if (COUNT_POS) np += __shfl_down(np, off);
    }
    if (l == 0) { red[w*4+0]=ll; red[w*4+1]=lc; red[w*4+2]=lk; red[w*4+3]=np; }
    __syncthreads();
    if (tid == 0) {
        float s0=0, s1=0, s2=0, s3=0;
        for (int ww = 0; ww < 4; ++ww) { s0+=red[ww*4+0]; s1+=red[ww*4+1]; s2+=red[ww*4+2]; s3+=red[ww*4+3]; }
        atomicAdd(&acc[0], (double)s0);
        atomicAdd(&acc[1], (double)s1);
        atomicAdd(&acc[2], (double)s2);
        if (COUNT_POS) atomicAdd(&acc[3], (double)s3);
    }
}

// block counts: S52 VW4: ceil(8112/256)=32/img -> 1024; S26 VW4: ceil(2028/256)=8 -> 256;
// S13 VW1: ceil(507/64)=8 -> 256.  Total 1536 blocks = 6144 waves.
constexpr int NBLK2 = NB * ((NA*52*52 + 255) / 256);
constexpr int NBLK1 = NB * ((NA*26*26 + 255) / 256);
constexpr int NBLK0 = NB * ((NA*13*13 + 63) / 64);

__global__ __launch_bounds__(256, 4) void yolo_all_kernel(
    const float* __restrict__ o0, const float* __restrict__ lo0, const float* __restrict__ c0, const float* __restrict__ bx0,
    const float* __restrict__ o1, const float* __restrict__ lo1, const float* __restrict__ c1, const float* __restrict__ bx1,
    const float* __restrict__ o2, const float* __restrict__ lo2, const float* __restrict__ c2, const float* __restrict__ bx2,
    double* __restrict__ acc)
{
    __shared__ float smem[SMEM_FLOATS];
    const int bid = blockIdx.x;
    if (bid < NBLK2) {
        process_scale<2, 52, 4, false>(o2, lo2, c2, bx2, acc, smem, bid);
    } else if (bid < NBLK2 + NBLK1) {
        process_scale<1, 26, 4, false>(o1, lo1, c1, bx1, acc, smem, bid - NBLK2);
    } else {
        process_scale<0, 13, 1, true>(o0, lo0, c0, bx0, acc, smem, bid - NBLK2 - NBLK1);
    }
}

extern "C" void kernel_launch(void* const* d_in, const int* in_sizes, int n_in,
                              void* d_out, int out_size, void* d_ws, size_t ws_size,
                              hipStream_t stream) {
    (void)in_sizes; (void)n_in; (void)out_size; (void)ws_size;
    const float* o0  = (const float*)d_in[0];
    const float* lo0 = (const float*)d_in[1];
    const float* c0  = (const float*)d_in[2];
    const float* bx0 = (const float*)d_in[3];
    const float* o1  = (const float*)d_in[4];
    const float* lo1 = (const float*)d_in[5];
    const float* c1  = (const float*)d_in[6];
    const float* bx1 = (const float*)d_in[7];
    const float* o2  = (const float*)d_in[8];
    const float* lo2 = (const float*)d_in[9];
    const float* c2  = (const float*)d_in[10];
    const float* bx2 = (const float*)d_in[11];

    double* acc = (double*)d_ws;
    float* out = (float*)d_out;

    init_acc_kernel<<<1, 64, 0, stream>>>(acc);
    yolo_all_kernel<<<NBLK2 + NBLK1 + NBLK0, 256, 0, stream>>>(
        o0, lo0, c0, bx0, o1, lo1, c1, bx1, o2, lo2, c2, bx2, acc);
    finalize_kernel<<<1, 1, 0, stream>>>(acc, out);
}

// Round 5
// 60.717 us; speedup vs baseline: 1.5725x; 1.5725x over previous
//
#include <hip/hip_runtime.h>
#include <cstddef>

// YOLOv3 loss, MI355X. b=32, scales 13/26/52, 3 anchors, 80 classes, 50 boxes.
// Input order (setup_inputs dict order, interleaved per scale):
//   d_in[4k+0]=output_k (b,255,S,S)  d_in[4k+1]=loc_k (b,3,4,S,S)
//   d_in[4k+2]=cls_k (b,3,80,S,S)    d_in[4k+3]=boxes_k (b,50,4)
// ws: 4 doubles {LL, LC, LK, NPOS}
//
// R4 = R1 structure (best measured: 59.6us) + deeper memory ILP:
//  - explicit 8-channel batches: 16 float4 loads issued before any consume
//  - tail loads (op[0:5], loc) hoisted in front of the class loop
//  - no occupancy hint: grid caps occupancy at 18.75%, so VGPR<=160 is free

constexpr int NC = 80;
constexpr int NA = 3;
constexpr int NM = 50;
constexpr int NB = 32;

__device__ constexpr float ANCW[3][3] = {{116.f,156.f,373.f},{30.f,62.f,59.f},{10.f,16.f,33.f}};
__device__ constexpr float ANCH[3][3] = {{ 90.f,198.f,326.f},{61.f,45.f,119.f},{13.f,30.f,23.f}};

__device__ __forceinline__ float frcp_(float x) { return __builtin_amdgcn_rcpf(x); }
__device__ __forceinline__ float sigmoidf_(float x) { return frcp_(1.0f + __expf(-x)); }

template <int VW>
__device__ __forceinline__ void loadv(const float* __restrict__ p, float (&d)[VW]) {
    if constexpr (VW == 4) {
        const float4 v = *reinterpret_cast<const float4*>(p);
        d[0] = v.x; d[1] = v.y; d[2] = v.z; d[3] = v.w;
    } else {
        d[0] = p[0];
    }
}

__global__ void init_acc_kernel(double* acc) {
    if (threadIdx.x < 4) acc[threadIdx.x] = 0.0;
}

__global__ void finalize_kernel(const double* __restrict__ acc, float* __restrict__ out) {
    out[0] = (float)(5.0 * (acc[0] + acc[1] + acc[2]) / (double)NB / acc[3]);
}

template <int SC, int S, int VW, bool COUNT_POS>
__device__ __forceinline__ void process_scale(
    const float* __restrict__ outp, const float* __restrict__ locp,
    const float* __restrict__ clsp, const float* __restrict__ boxp,
    double* __restrict__ acc, int rel)
{
    constexpr int SS = S * S;
    constexpr int CELLS = NA * SS;
    constexpr int TPB_CELLS = 256 * VW;
    constexpr int BPB = (CELLS + TPB_CELLS - 1) / TPB_CELLS;

    const int b   = rel / BPB;
    const int chk = rel % BPB;
    const int tid = threadIdx.x;

    __shared__ float sbx[NM * 4];
    __shared__ float sba[NM];
    __shared__ float red[4][4];

    if (tid < NM * 4) sbx[tid] = boxp[(size_t)b * NM * 4 + tid];
    __syncthreads();
    if (tid < NM)
        sba[tid] = (sbx[tid*4+2] - sbx[tid*4+0]) * (sbx[tid*4+3] - sbx[tid*4+1]);
    __syncthreads();

    float ll = 0.f, lc = 0.f, lk = 0.f, np = 0.f;

    const int cell0 = (chk * 256 + tid) * VW;
    if (cell0 < CELLS) {
        const int a   = cell0 / SS;
        const int rem = cell0 - a * SS;

        const float* op = outp + ((size_t)b * NA + a) * (5 + NC) * SS + rem;
        const float* cp = clsp + ((size_t)b * NA + a) * NC * SS + rem;
        const float* lp = locp + ((size_t)b * NA + a) * 4 * SS + rem;

        // ---- issue tail loads FIRST: they stay in flight under the class loop ----
        float tx[VW], ty[VW], tw[VW], th[VW], tc[VW];
        float l0[VW], l1[VW], l2[VW], l3[VW];
        loadv<VW>(op + 0 * SS, tx);
        loadv<VW>(op + 1 * SS, ty);
        loadv<VW>(op + 2 * SS, tw);
        loadv<VW>(op + 3 * SS, th);
        loadv<VW>(op + 4 * SS, tc);
        loadv<VW>(lp + 0 * SS, l0);
        loadv<VW>(lp + 1 * SS, l1);
        loadv<VW>(lp + 2 * SS, l2);
        loadv<VW>(lp + 3 * SS, l3);

        // ---- class loss: sum_{t>0}(p-t)^2 = A2/Z^2 - 2 A1/Z + A0 ----
        // 8-channel explicit batches: 16 float4 loads in flight before consume.
        float Z[VW] = {}, A2[VW] = {}, A1[VW] = {}, A0[VW] = {};
        const float* opc = op + (size_t)5 * SS;
        #pragma unroll 2
        for (int c0 = 0; c0 < NC; c0 += 8) {
            float L[8][VW], T[8][VW];
            #pragma unroll
            for (int j = 0; j < 8; ++j)
                loadv<VW>(opc + (size_t)(c0 + j) * SS, L[j]);
            #pragma unroll
            for (int j = 0; j < 8; ++j)
                loadv<VW>(cp + (size_t)(c0 + j) * SS, T[j]);
            #pragma unroll
            for (int j = 0; j < 8; ++j) {
                #pragma unroll
                for (int i = 0; i < VW; ++i) {
                    const float e  = __expf(L[j][i]);
                    const float wf = (T[j][i] > 0.f) ? 1.f : 0.f;
                    const float we = wf * e;
                    const float wt = wf * T[j][i];
                    Z[i]  += e;
                    A2[i]  = fmaf(we, e, A2[i]);
                    A1[i]  = fmaf(we, T[j][i], A1[i]);
                    A0[i]  = fmaf(wt, T[j][i], A0[i]);
                }
            }
        }

        const float aw = ANCW[SC][a] * ((float)S / 416.f);
        const float ah = ANCH[SC][a] * ((float)S / 416.f);

        float x1[VW], y1[VW], x2[VW], y2[VW], area[VW], bn[VW], bd[VW];
        bool pos[VW];
        #pragma unroll
        for (int i = 0; i < VW; ++i) {
            pos[i] = A0[i] > 0.f;
            const float d0 = tx[i]-l0[i], d1 = ty[i]-l1[i], d2 = tw[i]-l2[i], d3 = th[i]-l3[i];
            const float lli = d0*d0 + d1*d1 + d2*d2 + d3*d3;
            ll += pos[i] ? lli : 0.f;
            if (COUNT_POS) np += pos[i] ? 1.f : 0.f;

            const int ri = rem + i;
            const int y  = ri / S;
            const int x  = ri - y * S;
            const float sx = sigmoidf_(tx[i]) + (float)x;
            const float sy = sigmoidf_(ty[i]) + (float)y;
            const float bw = __expf(tw[i]) * aw;
            const float bh = __expf(th[i]) * ah;
            x1[i] = sx - bw * 0.5f;  y1[i] = sy - bh * 0.5f;
            x2[i] = sx + bw * 0.5f;  y2[i] = sy + bh * 0.5f;
            area[i] = (x2[i] - x1[i]) * (y2[i] - y1[i]);
            bn[i] = 0.f; bd[i] = 1.f;
        }

        // ---- max IoU vs 50 boxes, rational compare (no per-box divide) ----
        for (int j = 0; j < NM; ++j) {
            const float bx1 = sbx[j*4+0], by1 = sbx[j*4+1];
            const float bx2 = sbx[j*4+2], by2 = sbx[j*4+3];
            const float ab  = sba[j];
            #pragma unroll
            for (int i = 0; i < VW; ++i) {
                const float iw = fmaxf(fminf(x2[i], bx2) - fmaxf(x1[i], bx1), 0.f);
                const float ih = fmaxf(fminf(y2[i], by2) - fmaxf(y1[i], by1), 0.f);
                const float inter = iw * ih;
                const float uni   = area[i] + ab - inter;
                const bool upd = inter * bd[i] > bn[i] * uni;
                bn[i] = upd ? inter : bn[i];
                bd[i] = upd ? uni   : bd[i];
            }
        }

        #pragma unroll
        for (int i = 0; i < VW; ++i) {
            const float best  = bn[i] * frcp_(bd[i]);
            const float cpred = sigmoidf_(tc[i]);
            const float m2    = pos[i] ? 1.f : 0.01f;
            const float d     = cpred - best;
            lc += m2 * d * d;
            const float invZ = frcp_(Z[i]);
            lk += fmaf(A2[i] * invZ, invZ, fmaf(-2.f * A1[i], invZ, A0[i]));
        }
    }

    // ---- block reduction ----
    for (int off = 32; off > 0; off >>= 1) {
        ll += __shfl_down(ll, off);
        lc += __shfl_down(lc, off);
        lk += __shfl_down(lk, off);
        if (COUNT_POS) np += __shfl_down(np, off);
    }
    const int wave = tid >> 6, lane = tid & 63;
    if (lane == 0) { red[wave][0]=ll; red[wave][1]=lc; red[wave][2]=lk; red[wave][3]=np; }
    __syncthreads();
    if (tid == 0) {
        float s0=0, s1=0, s2=0, s3=0;
        for (int w = 0; w < 4; ++w) { s0+=red[w][0]; s1+=red[w][1]; s2+=red[w][2]; s3+=red[w][3]; }
        atomicAdd(&acc[0], (double)s0);
        atomicAdd(&acc[1], (double)s1);
        atomicAdd(&acc[2], (double)s2);
        if (COUNT_POS) atomicAdd(&acc[3], (double)s3);
    }
}

// block ranges: S=52 VW4 -> BPB 8 -> 256 blocks; S=26 VW4 -> 64; S=13 VW1 -> 64
constexpr int NBLK2 = NB * ((NA*52*52 + 1023) / 1024);   // 256
constexpr int NBLK1 = NB * ((NA*26*26 + 1023) / 1024);   // 64
constexpr int NBLK0 = NB * ((NA*13*13 + 255) / 256);     // 64

__global__ __launch_bounds__(256) void yolo_all_kernel(
    const float* __restrict__ o0, const float* __restrict__ lo0, const float* __restrict__ c0, const float* __restrict__ bx0,
    const float* __restrict__ o1, const float* __restrict__ lo1, const float* __restrict__ c1, const float* __restrict__ bx1,
    const float* __restrict__ o2, const float* __restrict__ lo2, const float* __restrict__ c2, const float* __restrict__ bx2,
    double* __restrict__ acc)
{
    const int bid = blockIdx.x;
    if (bid < NBLK2) {
        process_scale<2, 52, 4, false>(o2, lo2, c2, bx2, acc, bid);
    } else if (bid < NBLK2 + NBLK1) {
        process_scale<1, 26, 4, false>(o1, lo1, c1, bx1, acc, bid - NBLK2);
    } else {
        process_scale<0, 13, 1, true>(o0, lo0, c0, bx0, acc, bid - NBLK2 - NBLK1);
    }
}

extern "C" void kernel_launch(void* const* d_in, const int* in_sizes, int n_in,
                              void* d_out, int out_size, void* d_ws, size_t ws_size,
                              hipStream_t stream) {
    (void)in_sizes; (void)n_in; (void)out_size; (void)ws_size;
    const float* o0  = (const float*)d_in[0];
    const float* lo0 = (const float*)d_in[1];
    const float* c0  = (const float*)d_in[2];
    const float* bx0 = (const float*)d_in[3];
    const float* o1  = (const float*)d_in[4];
    const float* lo1 = (const float*)d_in[5];
    const float* c1  = (const float*)d_in[6];
    const float* bx1 = (const float*)d_in[7];
    const float* o2  = (const float*)d_in[8];
    const float* lo2 = (const float*)d_in[9];
    const float* c2  = (const float*)d_in[10];
    const float* bx2 = (const float*)d_in[11];

    double* acc = (double*)d_ws;
    float* out = (float*)d_out;

    init_acc_kernel<<<1, 64, 0, stream>>>(acc);
    yolo_all_kernel<<<NBLK2 + NBLK1 + NBLK0, 256, 0, stream>>>(
        o0, lo0, c0, bx0, o1, lo1, c1, bx1, o2, lo2, c2, bx2, acc);
    finalize_kernel<<<1, 1, 0, stream>>>(acc, out);
}